// Round 7
// baseline (350.474 us; speedup 1.0000x reference)
//
#include <hip/hip_runtime.h>
#include <math.h>

#define NB 16      // batch
#define NC 3       // obs channels
#define NN 3000    // nodes
#define NT 50      // time
#define NE 96000   // edges
#define NR 3       // relations
#define NS 500     // selected stocks
#define NF 43      // feature dim
#define NFP 44     // padded feature dim
#define NBF (NB*NFP)   // 704 = 11 * 64: transposed row length per node
#define NBKT (NR*NN)   // 9000 buckets keyed (rel, dst)
#define CAP 96     // fixed bucket capacity (mean 10.7; Poisson tail @96 ~ 0)

// ---------------- workspace layout (floats, then ints) ----------------
// x_t / h1_t: [node][b*44+f]  (704 floats per node)
// z:          [bucket-row][b*44+f]  (L1: 9000 rows; L2 reuses first 1500)
// h2:         [b][NS][NFP] compact
#define XT_OFF   0
#define H1_OFF   (XT_OFF + NN*NBF)
#define Z_OFF    (H1_OFF + NN*NBF)
#define H2_OFF   (Z_OFF  + NBKT*NBF)
#define INT_BASE (H2_OFF + NB*NS*NFP)
#define CNT_OFF  0
#define EBUF_OFF (CNT_OFF + NBKT)

// ---------------- fused front: temporal features + bucket fill ----------------
// blocks [0,750):   temporal (64 nodes x 4 t-slice waves, obs staged via LDS)
// blocks [750,1125): bucket fill (count + place, no scan)
__global__ __launch_bounds__(256, 2) void k_front(
    const float* __restrict__ obs,
    const float* __restrict__ ws1, const float* __restrict__ bs1,
    const float* __restrict__ ws2, const float* __restrict__ bs2,
    const float* __restrict__ wm1, const float* __restrict__ bm1,
    const float* __restrict__ wm2, const float* __restrict__ bm2,
    float* __restrict__ x,
    const int* __restrict__ ei, const int* __restrict__ et,
    int* __restrict__ cnt, int* __restrict__ ebuf)
{
    __shared__ float st[3][64][53];   // staged obs tile; stride 53: conflict-free
    __shared__ float sp[4][64][25];   // [wave][node][partial]
    int tid = threadIdx.x;

    if (blockIdx.x >= 750) {
        // ---- bucket fill ----
        int e = (blockIdx.x - 750) * 256 + tid;
        if (e < NE) {
            int bkt = et[e] * NN + ei[NE + e];
            int pos = atomicAdd(&cnt[bkt], 1);
            if (pos < CAP) ebuf[bkt * CAP + pos] = ei[e];  // src
        }
        return;
    }

    // ---- cooperative coalesced staging: 192 rows x 25 float2 ----
    int g0 = blockIdx.x * 64;
    for (int it = tid; it < 4800; it += 256) {
        int row = it / 25, j = it - row * 25;   // row = c*64 + i
        int c = row >> 6, i = row & 63;
        int g = g0 + i;
        int bb = g / NN, nn = g - bb * NN;
        const float2* p2 = (const float2*)(obs + ((size_t)(bb * NC + c) * NN + nn) * NT);
        float2 u = p2[j];
        st[c][i][2 * j]     = u.x;
        st[c][i][2 * j + 1] = u.y;
    }
    __syncthreads();

    int wave = __builtin_amdgcn_readfirstlane(tid >> 6);
    int lane = tid & 63;

    // ---- phase A: short conv stack, slice of 12 t's ----
    {
        float wS[3][14];
        int base = 12 * wave;
        #pragma unroll
        for (int c = 0; c < 3; ++c)
            #pragma unroll
            for (int t = 0; t < 14; ++t)
                wS[c][t] = st[c][lane][base + t];

        float acc[20];
        #pragma unroll
        for (int o = 0; o < 20; ++o) acc[o] = 0.f;
        #pragma unroll
        for (int j = 0; j < 12; ++j) {
            float y[3];
            #pragma unroll
            for (int c = 0; c < 3; ++c) {
                float s = bs1[c];
                #pragma unroll
                for (int i = 0; i < 3; ++i)
                    #pragma unroll
                    for (int k = 0; k < 3; ++k)
                        s = fmaf(wS[i][j + k], ws1[(c * 3 + i) * 3 + k], s);
                y[c] = fmaxf(s, 0.f);
            }
            int gt = base + j;   // wave-uniform -> scalar loads of ws2
            #pragma unroll
            for (int o = 0; o < 20; ++o) {
                float a = acc[o];
                #pragma unroll
                for (int c = 0; c < 3; ++c)
                    a = fmaf(y[c], ws2[(o * 3 + c) * 48 + gt], a);
                acc[o] = a;
            }
        }
        #pragma unroll
        for (int o = 0; o < 20; ++o) sp[wave][lane][o] = acc[o];
    }
    __syncthreads();
    // reduce short: 64 nodes x 20 outputs = 1280 = 5*256
    #pragma unroll
    for (int q = 0; q < 5; ++q) {
        int item = q * 256 + tid;
        int node = item / 20, o = item - node * 20;
        int g = blockIdx.x * 64 + node;
        int bb = g / NN, nn = g - bb * NN;
        float s = ((sp[0][node][o] + sp[1][node][o]) +
                   (sp[2][node][o] + sp[3][node][o])) + bs2[o];
        x[(size_t)nn * NBF + bb * NFP + o] = fmaxf(s, 0.f);
    }
    __syncthreads();

    // ---- phase B: mid conv stack + long max ----
    {
        float wM[3][28];
        int mbase = (wave < 3) ? 8 * wave : 24;
        int nv    = (wave < 3) ? 28 : 26;    // valid window floats (t <= 49)
        #pragma unroll
        for (int c = 0; c < 3; ++c)
            #pragma unroll
            for (int t = 0; t < 28; ++t)
                wM[c][t] = (t < nv) ? st[c][lane][mbase + t] : 0.f;

        float cmax[3];
        #pragma unroll
        for (int c = 0; c < 3; ++c) {
            float m = wM[c][0];
            #pragma unroll
            for (int t = 1; t < 28; ++t) m = fmaxf(m, wM[c][t]);
            cmax[c] = m;   // zero-pad safe: relu follows
        }
        float acc[20];
        #pragma unroll
        for (int o = 0; o < 20; ++o) acc[o] = 0.f;
        int cntM = (wave < 3) ? 8 : 6;
        #pragma unroll
        for (int j = 0; j < 8; ++j) {
            if (j < cntM) {
                float y[3];
                #pragma unroll
                for (int c = 0; c < 3; ++c) {
                    float s = bm1[c];
                    #pragma unroll
                    for (int i = 0; i < 3; ++i)
                        #pragma unroll
                        for (int k = 0; k < 21; ++k)
                            s = fmaf(wM[i][j + k], wm1[(c * 3 + i) * 21 + k], s);
                    y[c] = fmaxf(s, 0.f);
                }
                int gt = mbase + j;
                #pragma unroll
                for (int o = 0; o < 20; ++o) {
                    float a = acc[o];
                    #pragma unroll
                    for (int c = 0; c < 3; ++c)
                        a = fmaf(y[c], wm2[(o * 3 + c) * 30 + gt], a);
                    acc[o] = a;
                }
            }
        }
        #pragma unroll
        for (int o = 0; o < 20; ++o) sp[wave][lane][o] = acc[o];
        #pragma unroll
        for (int c = 0; c < 3; ++c) sp[wave][lane][20 + c] = cmax[c];
    }
    __syncthreads();
    // reduce mid + long: 64 nodes x 23 = 1472 items
    #pragma unroll
    for (int q = 0; q < 6; ++q) {
        int item = q * 256 + tid;
        if (item < 1472) {
            int node = item / 23, o = item - node * 23;
            int g = blockIdx.x * 64 + node;
            int bb = g / NN, nn = g - bb * NN;
            size_t row = (size_t)nn * NBF + bb * NFP;
            if (o < 20) {
                float s = ((sp[0][node][o] + sp[1][node][o]) +
                           (sp[2][node][o] + sp[3][node][o])) + bm2[o];
                x[row + 20 + o] = fmaxf(s, 0.f);
            } else {
                float m = fmaxf(fmaxf(sp[0][node][o], sp[1][node][o]),
                                fmaxf(sp[2][node][o], sp[3][node][o]));
                x[row + 40 + (o - 20)] = fmaxf(m, 0.f);
            }
        }
    }
}

// ---------------- RGCN aggregation (transposed): wave per bucket, all batches ----------------
// z[zrow][j*64+lane] = (1/max(cnt,1)) * sum_{src in bucket} act(in_t)[src][j*64+lane]
// 11 coalesced 256-B loads per edge (immediate offsets), int4 index prefetch.
template<bool LEAKY, bool SEL>
__global__ __launch_bounds__(256) void k_aggregate(
    const float* __restrict__ in, const int* __restrict__ cnt,
    const int* __restrict__ ebuf, const int* __restrict__ sel,
    float* __restrict__ z, int nbi)
{
    int wave = threadIdx.x >> 6, lane = threadIdx.x & 63;
    int bi = blockIdx.x * 4 + wave;
    if (bi >= nbi) return;

    int bkt;
    if (SEL) {
        int r = bi / NS, ii = bi - r * NS;
        int dst = __builtin_amdgcn_readfirstlane(sel[ii]);
        bkt = r * NN + dst;
    } else {
        bkt = bi;
    }
    int cvr = __builtin_amdgcn_readfirstlane(cnt[bkt]);
    float ic = 1.0f / fmaxf((float)cvr, 1.0f);
    int cv = cvr > CAP ? CAP : cvr;

    const int* eb = ebuf + bkt * CAP;
    float acc[11];
    #pragma unroll
    for (int j = 0; j < 11; ++j) acc[j] = 0.f;

    for (int e = 0; e < cv; e += 4) {
        int4 q = *(const int4*)(eb + e);   // 16B-aligned (CAP*4 = 384)
        int m = cv - e;
        {
            int s0 = __builtin_amdgcn_readfirstlane(q.x);
            const float* p = in + (size_t)s0 * NBF;
            #pragma unroll
            for (int j = 0; j < 11; ++j) {
                float v = p[j * 64 + lane];
                if (LEAKY) v = v >= 0.f ? v : 0.01f * v;
                acc[j] += v;
            }
        }
        if (m > 1) {
            int s1 = __builtin_amdgcn_readfirstlane(q.y);
            const float* p = in + (size_t)s1 * NBF;
            #pragma unroll
            for (int j = 0; j < 11; ++j) {
                float v = p[j * 64 + lane];
                if (LEAKY) v = v >= 0.f ? v : 0.01f * v;
                acc[j] += v;
            }
        }
        if (m > 2) {
            int s2 = __builtin_amdgcn_readfirstlane(q.z);
            const float* p = in + (size_t)s2 * NBF;
            #pragma unroll
            for (int j = 0; j < 11; ++j) {
                float v = p[j * 64 + lane];
                if (LEAKY) v = v >= 0.f ? v : 0.01f * v;
                acc[j] += v;
            }
        }
        if (m > 3) {
            int s3 = __builtin_amdgcn_readfirstlane(q.w);
            const float* p = in + (size_t)s3 * NBF;
            #pragma unroll
            for (int j = 0; j < 11; ++j) {
                float v = p[j * 64 + lane];
                if (LEAKY) v = v >= 0.f ? v : 0.01f * v;
                acc[j] += v;
            }
        }
    }

    float* zp = z + (size_t)bi * NBF;
    #pragma unroll
    for (int j = 0; j < 11; ++j) zp[j * 64 + lane] = acc[j] * ic;
}

// ---------------- RGCN dense transform, k-split across 4 waves ----------------
// wave 0: self row @ root; waves 1-3: z slab r @ rel_r. A-slabs are wave-uniform
// (s_load); weight columns live in VGPRs; cross-wave reduce via LDS.
template<bool LEAKY, bool SEL, int NDST, bool TOUT>
__global__ __launch_bounds__(256) void k_xform(
    const float* __restrict__ in, const float* __restrict__ z,
    const float* __restrict__ root, const float* __restrict__ rel,
    const float* __restrict__ bias, const int* __restrict__ sel,
    float* __restrict__ out)
{
    __shared__ float sP[8][4][NFP];   // [row-in-chunk][wave][feature]

    int wave = __builtin_amdgcn_readfirstlane(threadIdx.x >> 6);
    int lane = threadIdx.x & 63;
    int rowbase = blockIdx.x * 16;

    const float* wbase = (wave == 0) ? root : (rel + (size_t)(wave - 1) * NF * NF);
    float wsl[43];
    #pragma unroll
    for (int j = 0; j < 43; ++j)
        wsl[j] = (lane < NF) ? wbase[j * NF + lane] : 0.f;

    for (int rr8 = 0; rr8 < 16; rr8 += 8) {
        #pragma unroll 1
        for (int rr = 0; rr < 8; ++rr) {
            int t = rowbase + rr8 + rr;
            int b = t / NDST, i = t - b * NDST;
            const float* arow;
            if (wave == 0) {
                int node = SEL ? sel[i] : i;
                arow = in + (size_t)node * NBF + b * NFP;
            } else {
                int zrow = (wave - 1) * NDST + i;
                arow = z + (size_t)zrow * NBF + b * NFP;
            }
            float a0 = 0.f, a1 = 0.f, a2 = 0.f, a3 = 0.f;
            #pragma unroll
            for (int j = 0; j < 40; j += 4) {
                float v0 = arow[j], v1 = arow[j + 1], v2 = arow[j + 2], v3 = arow[j + 3];
                if (LEAKY && wave == 0) {
                    v0 = v0 >= 0.f ? v0 : 0.01f * v0;
                    v1 = v1 >= 0.f ? v1 : 0.01f * v1;
                    v2 = v2 >= 0.f ? v2 : 0.01f * v2;
                    v3 = v3 >= 0.f ? v3 : 0.01f * v3;
                }
                a0 = fmaf(v0, wsl[j], a0);
                a1 = fmaf(v1, wsl[j + 1], a1);
                a2 = fmaf(v2, wsl[j + 2], a2);
                a3 = fmaf(v3, wsl[j + 3], a3);
            }
            {
                float v0 = arow[40], v1 = arow[41], v2 = arow[42];
                if (LEAKY && wave == 0) {
                    v0 = v0 >= 0.f ? v0 : 0.01f * v0;
                    v1 = v1 >= 0.f ? v1 : 0.01f * v1;
                    v2 = v2 >= 0.f ? v2 : 0.01f * v2;
                }
                a0 = fmaf(v0, wsl[40], a0);
                a1 = fmaf(v1, wsl[41], a1);
                a2 = fmaf(v2, wsl[42], a2);
            }
            if (lane < NF) sP[rr][wave][lane] = (a0 + a1) + (a2 + a3);
        }
        __syncthreads();
        if (lane < NF) {
            int r0 = 2 * wave, r1 = 2 * wave + 1;
            float bi_ = bias[lane];
            float s0 = ((sP[r0][0][lane] + sP[r0][1][lane]) +
                        (sP[r0][2][lane] + sP[r0][3][lane])) + bi_;
            float s1 = ((sP[r1][0][lane] + sP[r1][1][lane]) +
                        (sP[r1][2][lane] + sP[r1][3][lane])) + bi_;
            int t0 = rowbase + rr8 + r0, t1 = rowbase + rr8 + r1;
            if (TOUT) {
                int b0 = t0 / NDST, i0 = t0 - b0 * NDST;
                int b1 = t1 / NDST, i1 = t1 - b1 * NDST;
                out[(size_t)i0 * NBF + b0 * NFP + lane] = s0;
                out[(size_t)i1 * NBF + b1 * NFP + lane] = s1;
            } else {
                out[(size_t)t0 * NFP + lane] = s0;
                out[(size_t)t1 * NFP + lane] = s1;
            }
        }
        __syncthreads();
    }
}

// ---------------- epilogue: gather + 1x1 conv + softmax ----------------
__device__ inline float wred_max(float v) {
    #pragma unroll
    for (int o = 32; o > 0; o >>= 1) v = fmaxf(v, __shfl_down(v, o));
    return v;
}
__device__ inline float wred_sum(float v) {
    #pragma unroll
    for (int o = 32; o > 0; o >>= 1) v += __shfl_down(v, o);
    return v;
}

__global__ __launch_bounds__(512) void k_final(
    const float* __restrict__ x, const float* __restrict__ h2,
    const float* __restrict__ la, const int* __restrict__ nodes,
    const float* __restrict__ wf, const float* __restrict__ bf,
    float* __restrict__ out)
{
    __shared__ float sl[NS + 1];
    __shared__ float sred[8];
    __shared__ float sbc[2];
    int b = blockIdx.x, tid = threadIdx.x;

    if (tid < NS) {
        int node = nodes[tid];
        float acc = bf[0] + wf[0] * la[b * (NS + 1) + 1 + tid];
        const float* xp = x  + (size_t)node * NBF + b * NFP;   // transposed x
        const float* hp = h2 + ((size_t)b * NS + tid) * NFP;   // compact h2
        #pragma unroll
        for (int c = 0; c < NF; ++c) acc = fmaf(wf[1 + c], xp[c], acc);
        #pragma unroll
        for (int c = 0; c < NF; ++c) {
            float t = hp[c];
            t = t >= 0.f ? t : 0.01f * t;   // leaky relu on RGCN2 output
            acc = fmaf(wf[44 + c], t, acc);
        }
        sl[tid + 1] = acc;
    }
    if (tid == 0) sl[0] = 0.f;   // cash logit
    __syncthreads();

    float m = (tid < NS + 1) ? sl[tid] : -3.0e38f;
    m = wred_max(m);
    if ((tid & 63) == 0) sred[tid >> 6] = m;
    __syncthreads();
    if (tid == 0) {
        float mm = sred[0];
        #pragma unroll
        for (int i = 1; i < 8; ++i) mm = fmaxf(mm, sred[i]);
        sbc[0] = mm;
    }
    __syncthreads();
    float mx = sbc[0];
    float e = (tid < NS + 1) ? expf(sl[tid] - mx) : 0.f;
    float s = wred_sum(e);
    if ((tid & 63) == 0) sred[tid >> 6] = s;
    __syncthreads();
    if (tid == 0) {
        float t = 0.f;
        #pragma unroll
        for (int i = 0; i < 8; ++i) t += sred[i];
        sbc[1] = t;
    }
    __syncthreads();
    if (tid < NS + 1) out[(size_t)b * (NS + 1) + tid] = e / sbc[1];
}

extern "C" void kernel_launch(void* const* d_in, const int* in_sizes, int n_in,
                              void* d_out, int out_size, void* d_ws, size_t ws_size,
                              hipStream_t stream)
{
    const float* obs   = (const float*)d_in[0];
    const float* la    = (const float*)d_in[1];
    const int*   ei    = (const int*)d_in[2];
    const int*   et    = (const int*)d_in[3];
    const int*   nodes = (const int*)d_in[4];
    const float* ws1 = (const float*)d_in[5],  *bs1 = (const float*)d_in[6];
    const float* ws2 = (const float*)d_in[7],  *bs2 = (const float*)d_in[8];
    const float* wm1 = (const float*)d_in[9],  *bm1 = (const float*)d_in[10];
    const float* wm2 = (const float*)d_in[11], *bm2 = (const float*)d_in[12];
    const float* root1 = (const float*)d_in[13], *rel1 = (const float*)d_in[14], *bias1 = (const float*)d_in[15];
    const float* root2 = (const float*)d_in[16], *rel2 = (const float*)d_in[17], *bias2 = (const float*)d_in[18];
    const float* wf = (const float*)d_in[19], *bf = (const float*)d_in[20];

    float* wsp = (float*)d_ws;
    float* x   = wsp + XT_OFF;
    float* h1  = wsp + H1_OFF;
    float* z   = wsp + Z_OFF;
    float* h2  = wsp + H2_OFF;
    int*   ibase = (int*)(wsp + INT_BASE);
    int*   cnt   = ibase + CNT_OFF;
    int*   ebuf  = ibase + EBUF_OFF;

    hipMemsetAsync(cnt, 0, NBKT * sizeof(int), stream);

    // fused: temporal features (blocks 0..749) + bucket fill (blocks 750..1124)
    k_front<<<750 + NE / 256, 256, 0, stream>>>(
        obs, ws1, bs1, ws2, bs2, wm1, bm1, wm2, bm2, x, ei, et, cnt, ebuf);

    // RGCN layer 1: all 9000 buckets, all batches per wave
    k_aggregate<false, false><<<NBKT / 4, 256, 0, stream>>>(
        x, cnt, ebuf, nullptr, z, NBKT);
    k_xform<false, false, NN, true><<<NB * NN / 16, 256, 0, stream>>>(
        x, z, root1, rel1, bias1, nullptr, h1);

    // RGCN layer 2: 1500 buckets (3 rel x 500 selected dst)
    k_aggregate<true, true><<<(NR * NS) / 4, 256, 0, stream>>>(
        h1, cnt, ebuf, nodes, z, NR * NS);
    k_xform<true, true, NS, false><<<NB * NS / 16, 256, 0, stream>>>(
        h1, z, root2, rel2, bias2, nodes, h2);

    k_final<<<NB, 512, 0, stream>>>(x, h2, la, nodes, wf, bf, (float*)d_out);
}

// Round 8
// 263.723 us; speedup vs baseline: 1.3289x; 1.3289x over previous
//
#include <hip/hip_runtime.h>
#include <math.h>

#define NB 16      // batch
#define NC 3       // obs channels
#define NN 3000    // nodes
#define NT 50      // time
#define NE 96000   // edges
#define NR 3       // relations
#define NS 500     // selected stocks
#define NF 43      // feature dim
#define NFP 44     // padded feature dim
#define NBF (NB*NFP)   // 704 = 11 * 64: transposed row length per node
#define NBKT (NR*NN)   // 9000 buckets keyed (rel, dst)
#define CAP 96     // fixed bucket capacity (mean 10.7; Poisson tail @96 ~ 0)

// ---------------- workspace layout (floats, then ints) ----------------
// x_t / h1_t: [node][b*44+f]  (704 floats per node)
// z:          [bucket-row][b*44+f]
// h2:         [b][NS][NFP] compact
#define XT_OFF   0
#define H1_OFF   (XT_OFF + NN*NBF)
#define Z_OFF    (H1_OFF + NN*NBF)
#define H2_OFF   (Z_OFF  + NBKT*NBF)
#define INT_BASE (H2_OFF + NB*NS*NFP)
#define CNT_OFF  0
#define EBUF_OFF (CNT_OFF + NBKT)

// ---------------- fused front: temporal features (A/B split) + bucket fill ----------------
// blocks [0,750):    phase A: short conv (t-sliced over 4 waves)
// blocks [750,1500): phase B: mid conv (channel-at-a-time) + long max
// blocks [1500,1875): bucket fill (count + place, no scan)
__global__ __launch_bounds__(256, 4) void k_front(
    const float* __restrict__ obs,
    const float* __restrict__ ws1, const float* __restrict__ bs1,
    const float* __restrict__ ws2, const float* __restrict__ bs2,
    const float* __restrict__ wm1, const float* __restrict__ bm1,
    const float* __restrict__ wm2, const float* __restrict__ bm2,
    float* __restrict__ x,
    const int* __restrict__ ei, const int* __restrict__ et,
    int* __restrict__ cnt, int* __restrict__ ebuf)
{
    __shared__ float sp[4][64][23];   // [wave][node][partial]
    int tid = threadIdx.x;

    if (blockIdx.x >= 1500) {
        // ---- bucket fill: 375 blocks x 256 = 96000 exact ----
        int e = (blockIdx.x - 1500) * 256 + tid;
        int bkt = et[e] * NN + ei[NE + e];
        int pos = atomicAdd(&cnt[bkt], 1);
        if (pos < CAP) ebuf[bkt * CAP + pos] = ei[e];  // src
        return;
    }

    int wave = __builtin_amdgcn_readfirstlane(tid >> 6);
    int lane = tid & 63;

    if (blockIdx.x < 750) {
        // ---- phase A: short conv, slice of 12 t's per wave ----
        int idx = blockIdx.x * 64 + lane;
        int b = idx / NN, n = idx - b * NN;
        float wS[3][14];
        int base = 12 * wave;
        #pragma unroll
        for (int c = 0; c < 3; ++c) {
            const float2* p2 = (const float2*)(obs + ((size_t)(b * NC + c) * NN + n) * NT + base);
            #pragma unroll
            for (int jj = 0; jj < 7; ++jj) {
                float2 u = p2[jj];
                wS[c][2 * jj] = u.x; wS[c][2 * jj + 1] = u.y;
            }
        }
        float acc[20];
        #pragma unroll
        for (int o = 0; o < 20; ++o) acc[o] = 0.f;
        #pragma unroll
        for (int j = 0; j < 12; ++j) {
            float y[3];
            #pragma unroll
            for (int c = 0; c < 3; ++c) {
                float s = bs1[c];
                #pragma unroll
                for (int i = 0; i < 3; ++i)
                    #pragma unroll
                    for (int k = 0; k < 3; ++k)
                        s = fmaf(wS[i][j + k], ws1[(c * 3 + i) * 3 + k], s);
                y[c] = fmaxf(s, 0.f);
            }
            int gt = base + j;   // wave-uniform -> scalar loads of ws2
            #pragma unroll
            for (int o = 0; o < 20; ++o) {
                float a = acc[o];
                #pragma unroll
                for (int c = 0; c < 3; ++c)
                    a = fmaf(y[c], ws2[(o * 3 + c) * 48 + gt], a);
                acc[o] = a;
            }
        }
        #pragma unroll
        for (int o = 0; o < 20; ++o) sp[wave][lane][o] = acc[o];
        __syncthreads();
        // reduce: 64 nodes x 20 outputs = 1280 = 5*256
        #pragma unroll
        for (int q = 0; q < 5; ++q) {
            int item = q * 256 + tid;
            int node = item / 20, o = item - node * 20;
            int g = blockIdx.x * 64 + node;
            int bb = g / NN, nn = g - bb * NN;
            float s = ((sp[0][node][o] + sp[1][node][o]) +
                       (sp[2][node][o] + sp[3][node][o])) + bs2[o];
            x[(size_t)nn * NBF + bb * NFP + o] = fmaxf(s, 0.f);
        }
        return;
    }

    // ---- phase B: mid conv (channel-at-a-time) + long max ----
    {
        int idx = (blockIdx.x - 750) * 64 + lane;
        int b = idx / NN, n = idx - b * NN;
        int mbase = (wave < 3) ? 8 * wave : 24;
        int nld   = (wave < 3) ? 14 : 13;    // float2 count (window 28 / 26)

        float s[3][8];
        #pragma unroll
        for (int c = 0; c < 3; ++c)
            #pragma unroll
            for (int t = 0; t < 8; ++t) s[c][t] = bm1[c];
        float cmax[3];

        #pragma unroll 1
        for (int i = 0; i < 3; ++i) {
            float win[28];
            const float2* p2 = (const float2*)(obs + ((size_t)(b * NC + i) * NN + n) * NT + mbase);
            #pragma unroll
            for (int jj = 0; jj < 14; ++jj) {
                if (jj < nld) {
                    float2 u = p2[jj];
                    win[2 * jj] = u.x; win[2 * jj + 1] = u.y;
                } else {
                    win[2 * jj] = 0.f; win[2 * jj + 1] = 0.f;
                }
            }
            float m = win[0];
            #pragma unroll
            for (int t = 1; t < 28; ++t) m = fmaxf(m, win[t]);
            cmax[i] = m;   // zero-pad safe: relu follows
            #pragma unroll
            for (int c = 0; c < 3; ++c)
                #pragma unroll
                for (int t = 0; t < 8; ++t) {
                    float a = s[c][t];
                    #pragma unroll
                    for (int k = 0; k < 21; ++k)
                        a = fmaf(win[t + k], wm1[(c * 3 + i) * 21 + k], a);
                    s[c][t] = a;
                }
        }

        float acc[20];
        #pragma unroll
        for (int o = 0; o < 20; ++o) acc[o] = 0.f;
        int cntM = (wave < 3) ? 8 : 6;
        #pragma unroll
        for (int j = 0; j < 8; ++j) {
            if (j < cntM) {
                float y0 = fmaxf(s[0][j], 0.f);
                float y1 = fmaxf(s[1][j], 0.f);
                float y2 = fmaxf(s[2][j], 0.f);
                int gt = mbase + j;   // wave-uniform -> scalar loads of wm2
                #pragma unroll
                for (int o = 0; o < 20; ++o) {
                    float a = acc[o];
                    a = fmaf(y0, wm2[(o * 3 + 0) * 30 + gt], a);
                    a = fmaf(y1, wm2[(o * 3 + 1) * 30 + gt], a);
                    a = fmaf(y2, wm2[(o * 3 + 2) * 30 + gt], a);
                    acc[o] = a;
                }
            }
        }
        #pragma unroll
        for (int o = 0; o < 20; ++o) sp[wave][lane][o] = acc[o];
        #pragma unroll
        for (int c = 0; c < 3; ++c) sp[wave][lane][20 + c] = cmax[c];
    }
    __syncthreads();
    // reduce mid + long: 64 nodes x 23 = 1472 items
    #pragma unroll
    for (int q = 0; q < 6; ++q) {
        int item = q * 256 + tid;
        if (item < 1472) {
            int node = item / 23, o = item - node * 23;
            int g = (blockIdx.x - 750) * 64 + node;
            int bb = g / NN, nn = g - bb * NN;
            size_t row = (size_t)nn * NBF + bb * NFP;
            if (o < 20) {
                float s = ((sp[0][node][o] + sp[1][node][o]) +
                           (sp[2][node][o] + sp[3][node][o])) + bm2[o];
                x[row + 20 + o] = fmaxf(s, 0.f);
            } else {
                float m = fmaxf(fmaxf(sp[0][node][o], sp[1][node][o]),
                                fmaxf(sp[2][node][o], sp[3][node][o]));
                x[row + 40 + (o - 20)] = fmaxf(m, 0.f);
            }
        }
    }
}

// ---------------- RGCN aggregation (transposed): wave per bucket, all batches ----------------
// z[zrow][j*64+lane] = (1/max(cnt,1)) * sum_{src in bucket} act(in_t)[src][j*64+lane]
// 11 coalesced 256-B loads per edge (immediate offsets), int4 index prefetch.
template<bool LEAKY, bool SEL>
__global__ __launch_bounds__(256) void k_aggregate(
    const float* __restrict__ in, const int* __restrict__ cnt,
    const int* __restrict__ ebuf, const int* __restrict__ sel,
    float* __restrict__ z, int nbi)
{
    int wave = threadIdx.x >> 6, lane = threadIdx.x & 63;
    int bi = blockIdx.x * 4 + wave;
    if (bi >= nbi) return;

    int bkt;
    if (SEL) {
        int r = bi / NS, ii = bi - r * NS;
        int dst = __builtin_amdgcn_readfirstlane(sel[ii]);
        bkt = r * NN + dst;
    } else {
        bkt = bi;
    }
    int cvr = __builtin_amdgcn_readfirstlane(cnt[bkt]);
    float ic = 1.0f / fmaxf((float)cvr, 1.0f);
    int cv = cvr > CAP ? CAP : cvr;

    const int* eb = ebuf + bkt * CAP;
    float acc[11];
    #pragma unroll
    for (int j = 0; j < 11; ++j) acc[j] = 0.f;

    for (int e = 0; e < cv; e += 4) {
        int4 q = *(const int4*)(eb + e);   // 16B-aligned (CAP*4 = 384)
        int m = cv - e;
        {
            int s0 = __builtin_amdgcn_readfirstlane(q.x);
            const float* p = in + (size_t)s0 * NBF;
            #pragma unroll
            for (int j = 0; j < 11; ++j) {
                float v = p[j * 64 + lane];
                if (LEAKY) v = v >= 0.f ? v : 0.01f * v;
                acc[j] += v;
            }
        }
        if (m > 1) {
            int s1 = __builtin_amdgcn_readfirstlane(q.y);
            const float* p = in + (size_t)s1 * NBF;
            #pragma unroll
            for (int j = 0; j < 11; ++j) {
                float v = p[j * 64 + lane];
                if (LEAKY) v = v >= 0.f ? v : 0.01f * v;
                acc[j] += v;
            }
        }
        if (m > 2) {
            int s2 = __builtin_amdgcn_readfirstlane(q.z);
            const float* p = in + (size_t)s2 * NBF;
            #pragma unroll
            for (int j = 0; j < 11; ++j) {
                float v = p[j * 64 + lane];
                if (LEAKY) v = v >= 0.f ? v : 0.01f * v;
                acc[j] += v;
            }
        }
        if (m > 3) {
            int s3 = __builtin_amdgcn_readfirstlane(q.w);
            const float* p = in + (size_t)s3 * NBF;
            #pragma unroll
            for (int j = 0; j < 11; ++j) {
                float v = p[j * 64 + lane];
                if (LEAKY) v = v >= 0.f ? v : 0.01f * v;
                acc[j] += v;
            }
        }
    }

    float* zp = z + (size_t)bi * NBF;
    #pragma unroll
    for (int j = 0; j < 11; ++j) zp[j * 64 + lane] = acc[j] * ic;
}

// ---------------- RGCN dense transform, k-split across 4 waves ----------------
// wave 0: self row @ root; waves 1-3: z slab r @ rel_r. A-slabs are wave-uniform
// (s_load); weight columns live in VGPRs; cross-wave reduce via LDS.
template<bool LEAKY, bool SEL, int NDST, bool TOUT>
__global__ __launch_bounds__(256) void k_xform(
    const float* __restrict__ in, const float* __restrict__ z,
    const float* __restrict__ root, const float* __restrict__ rel,
    const float* __restrict__ bias, const int* __restrict__ sel,
    float* __restrict__ out)
{
    __shared__ float sP[8][4][NFP];   // [row-in-chunk][wave][feature]

    int wave = __builtin_amdgcn_readfirstlane(threadIdx.x >> 6);
    int lane = threadIdx.x & 63;
    int rowbase = blockIdx.x * 16;

    const float* wbase = (wave == 0) ? root : (rel + (size_t)(wave - 1) * NF * NF);
    float wsl[43];
    #pragma unroll
    for (int j = 0; j < 43; ++j)
        wsl[j] = (lane < NF) ? wbase[j * NF + lane] : 0.f;

    for (int rr8 = 0; rr8 < 16; rr8 += 8) {
        #pragma unroll 1
        for (int rr = 0; rr < 8; ++rr) {
            int t = rowbase + rr8 + rr;
            int b = t / NDST, i = t - b * NDST;
            const float* arow;
            if (wave == 0) {
                int node = SEL ? sel[i] : i;
                arow = in + (size_t)node * NBF + b * NFP;
            } else {
                int zrow = (wave - 1) * NDST + i;
                arow = z + (size_t)zrow * NBF + b * NFP;
            }
            float a0 = 0.f, a1 = 0.f, a2 = 0.f, a3 = 0.f;
            #pragma unroll
            for (int j = 0; j < 40; j += 4) {
                float v0 = arow[j], v1 = arow[j + 1], v2 = arow[j + 2], v3 = arow[j + 3];
                if (LEAKY && wave == 0) {
                    v0 = v0 >= 0.f ? v0 : 0.01f * v0;
                    v1 = v1 >= 0.f ? v1 : 0.01f * v1;
                    v2 = v2 >= 0.f ? v2 : 0.01f * v2;
                    v3 = v3 >= 0.f ? v3 : 0.01f * v3;
                }
                a0 = fmaf(v0, wsl[j], a0);
                a1 = fmaf(v1, wsl[j + 1], a1);
                a2 = fmaf(v2, wsl[j + 2], a2);
                a3 = fmaf(v3, wsl[j + 3], a3);
            }
            {
                float v0 = arow[40], v1 = arow[41], v2 = arow[42];
                if (LEAKY && wave == 0) {
                    v0 = v0 >= 0.f ? v0 : 0.01f * v0;
                    v1 = v1 >= 0.f ? v1 : 0.01f * v1;
                    v2 = v2 >= 0.f ? v2 : 0.01f * v2;
                }
                a0 = fmaf(v0, wsl[40], a0);
                a1 = fmaf(v1, wsl[41], a1);
                a2 = fmaf(v2, wsl[42], a2);
            }
            if (lane < NF) sP[rr][wave][lane] = (a0 + a1) + (a2 + a3);
        }
        __syncthreads();
        if (lane < NF) {
            int r0 = 2 * wave, r1 = 2 * wave + 1;
            float bi_ = bias[lane];
            float s0 = ((sP[r0][0][lane] + sP[r0][1][lane]) +
                        (sP[r0][2][lane] + sP[r0][3][lane])) + bi_;
            float s1 = ((sP[r1][0][lane] + sP[r1][1][lane]) +
                        (sP[r1][2][lane] + sP[r1][3][lane])) + bi_;
            int t0 = rowbase + rr8 + r0, t1 = rowbase + rr8 + r1;
            if (TOUT) {
                int b0 = t0 / NDST, i0 = t0 - b0 * NDST;
                int b1 = t1 / NDST, i1 = t1 - b1 * NDST;
                out[(size_t)i0 * NBF + b0 * NFP + lane] = s0;
                out[(size_t)i1 * NBF + b1 * NFP + lane] = s1;
            } else {
                out[(size_t)t0 * NFP + lane] = s0;
                out[(size_t)t1 * NFP + lane] = s1;
            }
        }
        __syncthreads();
    }
}

// ---------------- epilogue: gather + 1x1 conv + softmax ----------------
__device__ inline float wred_max(float v) {
    #pragma unroll
    for (int o = 32; o > 0; o >>= 1) v = fmaxf(v, __shfl_down(v, o));
    return v;
}
__device__ inline float wred_sum(float v) {
    #pragma unroll
    for (int o = 32; o > 0; o >>= 1) v += __shfl_down(v, o);
    return v;
}

__global__ __launch_bounds__(512) void k_final(
    const float* __restrict__ x, const float* __restrict__ h2,
    const float* __restrict__ la, const int* __restrict__ nodes,
    const float* __restrict__ wf, const float* __restrict__ bf,
    float* __restrict__ out)
{
    __shared__ float sl[NS + 1];
    __shared__ float sred[8];
    __shared__ float sbc[2];
    int b = blockIdx.x, tid = threadIdx.x;

    if (tid < NS) {
        int node = nodes[tid];
        float acc = bf[0] + wf[0] * la[b * (NS + 1) + 1 + tid];
        const float* xp = x  + (size_t)node * NBF + b * NFP;   // transposed x
        const float* hp = h2 + ((size_t)b * NS + tid) * NFP;   // compact h2
        #pragma unroll
        for (int c = 0; c < NF; ++c) acc = fmaf(wf[1 + c], xp[c], acc);
        #pragma unroll
        for (int c = 0; c < NF; ++c) {
            float t = hp[c];
            t = t >= 0.f ? t : 0.01f * t;   // leaky relu on RGCN2 output
            acc = fmaf(wf[44 + c], t, acc);
        }
        sl[tid + 1] = acc;
    }
    if (tid == 0) sl[0] = 0.f;   // cash logit
    __syncthreads();

    float m = (tid < NS + 1) ? sl[tid] : -3.0e38f;
    m = wred_max(m);
    if ((tid & 63) == 0) sred[tid >> 6] = m;
    __syncthreads();
    if (tid == 0) {
        float mm = sred[0];
        #pragma unroll
        for (int i = 1; i < 8; ++i) mm = fmaxf(mm, sred[i]);
        sbc[0] = mm;
    }
    __syncthreads();
    float mx = sbc[0];
    float e = (tid < NS + 1) ? expf(sl[tid] - mx) : 0.f;
    float s = wred_sum(e);
    if ((tid & 63) == 0) sred[tid >> 6] = s;
    __syncthreads();
    if (tid == 0) {
        float t = 0.f;
        #pragma unroll
        for (int i = 0; i < 8; ++i) t += sred[i];
        sbc[1] = t;
    }
    __syncthreads();
    if (tid < NS + 1) out[(size_t)b * (NS + 1) + tid] = e / sbc[1];
}

extern "C" void kernel_launch(void* const* d_in, const int* in_sizes, int n_in,
                              void* d_out, int out_size, void* d_ws, size_t ws_size,
                              hipStream_t stream)
{
    const float* obs   = (const float*)d_in[0];
    const float* la    = (const float*)d_in[1];
    const int*   ei    = (const int*)d_in[2];
    const int*   et    = (const int*)d_in[3];
    const int*   nodes = (const int*)d_in[4];
    const float* ws1 = (const float*)d_in[5],  *bs1 = (const float*)d_in[6];
    const float* ws2 = (const float*)d_in[7],  *bs2 = (const float*)d_in[8];
    const float* wm1 = (const float*)d_in[9],  *bm1 = (const float*)d_in[10];
    const float* wm2 = (const float*)d_in[11], *bm2 = (const float*)d_in[12];
    const float* root1 = (const float*)d_in[13], *rel1 = (const float*)d_in[14], *bias1 = (const float*)d_in[15];
    const float* root2 = (const float*)d_in[16], *rel2 = (const float*)d_in[17], *bias2 = (const float*)d_in[18];
    const float* wf = (const float*)d_in[19], *bf = (const float*)d_in[20];

    float* wsp = (float*)d_ws;
    float* x   = wsp + XT_OFF;
    float* h1  = wsp + H1_OFF;
    float* z   = wsp + Z_OFF;
    float* h2  = wsp + H2_OFF;
    int*   ibase = (int*)(wsp + INT_BASE);
    int*   cnt   = ibase + CNT_OFF;
    int*   ebuf  = ibase + EBUF_OFF;

    hipMemsetAsync(cnt, 0, NBKT * sizeof(int), stream);

    // fused: phase A (0..749) + phase B (750..1499) + bucket fill (1500..1874)
    k_front<<<1875, 256, 0, stream>>>(
        obs, ws1, bs1, ws2, bs2, wm1, bm1, wm2, bm2, x, ei, et, cnt, ebuf);

    // RGCN layer 1: all 9000 buckets, all batches per wave
    k_aggregate<false, false><<<NBKT / 4, 256, 0, stream>>>(
        x, cnt, ebuf, nullptr, z, NBKT);
    k_xform<false, false, NN, true><<<NB * NN / 16, 256, 0, stream>>>(
        x, z, root1, rel1, bias1, nullptr, h1);

    // RGCN layer 2: 1500 buckets (3 rel x 500 selected dst)
    k_aggregate<true, true><<<(NR * NS) / 4, 256, 0, stream>>>(
        h1, cnt, ebuf, nodes, z, NR * NS);
    k_xform<true, true, NS, false><<<NB * NS / 16, 256, 0, stream>>>(
        h1, z, root2, rel2, bias2, nodes, h2);

    k_final<<<NB, 512, 0, stream>>>(x, h2, la, nodes, wf, bf, (float*)d_out);
}